// Round 11
// baseline (652.905 us; speedup 1.0000x reference)
//
#include <hip/hip_runtime.h>

#define XD 192
#define YD 192
#define CCH 3
#define IMG 224

// ---- ws layout (float offsets) ----
// padrow[t] = old[c][r][t-47] for t in [47, 239), zero elsewhere; t in [0,288)
#define PADW 288
#define OFF_PAD 0
#define N_PAD (CCH*XD*PADW)             // 165888
#define OFF_KI (OFF_PAD + N_PAD)
#define KI_LD 96                        // 94 taps + 2 zero pad
#define N_KI (94*KI_LD)
#define OFF_KE (OFF_KI + N_KI)
#define KE_LD 40                        // 38 taps + 2 zero pad
#define N_KE (38*KE_LD)
#define OFF_Z (OFF_KE + N_KE)           // 96 zeros (taps for out-of-range rows)
#define N_Z 96

#define N_OUT (CCH*XD*YD)               // 110592

// conv: 144 row-groups (4 output rows each) * 16 r-phases = 2304 waves = 576 blocks
#define NCONV 576
#define NAFF 9216                       // 36864 pixels / 4 waves per block

typedef __attribute__((ext_vector_type(4))) float f32x4;

// Prep: zero output, build shifted-pad activation rows, masked gamma-prescaled
// lateral kernels, and the zero-tap block in ws.
__global__ __launch_bounds__(256) void k_prep(
    const float* __restrict__ exw, const float* __restrict__ exm,
    const float* __restrict__ inw, const float* __restrict__ inm,
    const float* __restrict__ oldact, float* __restrict__ ws,
    float* __restrict__ out)
{
    const int TOT = N_OUT + N_PAD + N_KI + N_KE + N_Z;
    for (int idx = blockIdx.x * 256 + threadIdx.x; idx < TOT; idx += gridDim.x * 256) {
        if (idx < N_OUT) {
            out[idx] = 0.f;
        } else if (idx < N_OUT + N_PAD) {
            const int k = idx - N_OUT;
            const int t = k % PADW;
            const int rem = k / PADW;            // c*XD + r
            float v = 0.f;
            if (t >= 47 && t < 47 + YD)
                v = oldact[rem * YD + (t - 47)];
            ws[OFF_PAD + k] = v;
        } else if (idx < N_OUT + N_PAD + N_KI) {
            const int k = idx - N_OUT - N_PAD;
            const int i = k / KI_LD, j = k % KI_LD;
            ws[OFF_KI + k] = (j < 94) ? (-0.9f * inw[i * 94 + j] * inm[i * 94 + j]) : 0.f;
        } else if (idx < N_OUT + N_PAD + N_KI + N_KE) {
            const int k = idx - N_OUT - N_PAD - N_KI;
            const int i = k / KE_LD, j = k % KE_LD;
            ws[OFF_KE + k] = (j < 38) ? (0.9f * exw[i * 38 + j] * exm[i * 38 + j]) : 0.f;
        } else {
            ws[OFF_Z + (idx - N_OUT - N_PAD - N_KI - N_KE)] = 0.f;
        }
    }
}

// Fused kernel:
//  blocks [0, NCONV): lateral conv. One wave owns 4 consecutive output rows
//    (x0..x0+3) and 3 cols per lane. Per staged activation row r (wave-private
//    LDS slice, no barriers), 4 kernel rows i=d-k are applied -> 36 FMA per
//    3-float LDS refill (4x the reuse of round 8). Out-of-range rows read a
//    zero-tap block (branchless). Exc conv reuses the same staged row.
//  blocks [NCONV, ...): afferent, round-8 verbatim (asm 21-load batch).
__global__ __launch_bounds__(256, 3) void k_fused(
    const float* __restrict__ input, const float* __restrict__ affw,
    const float* __restrict__ affm, const int* __restrict__ rfstart,
    const float* __restrict__ ws, float* __restrict__ out)
{
    __shared__ float s_row[4][PADW];    // 4.6 KB; per-wave private slices

    const int bid = blockIdx.x;
    const int tid = threadIdx.x;

    if (bid < NCONV) {
        // ---------------- lateral conv ----------------
        const int w    = tid >> 6;
        const int lane = tid & 63;
        const int rgq  = bid * 4 + w;       // 0..2303
        const int q    = rgq & 15;          // r-phase 0..15
        const int rg   = rgq >> 4;          // row-group 0..143
        const int rowid0 = rg * 4;          // = c*192 + x0 (never straddles c)
        const int c    = rowid0 / XD;
        const int x0   = rowid0 - c * XD;

        float* srow = &s_row[w][0];
        const float* padc = ws + OFF_PAD + (size_t)(c * XD) * PADW;
        const int bix = 3 * lane;

        float acc[12];
        #pragma unroll
        for (int t = 0; t < 12; ++t) acc[t] = 0.f;

        for (int r = x0 - 47 + q; r <= x0 + 49; r += 16) {
            if ((unsigned)r >= (unsigned)XD) continue;   // wave-uniform
            const int d = r - x0 + 47;                   // 0..96

            // stage padrow r into this wave's LDS slice (coalesced)
            const float* src = padc + r * PADW;
            *(float4*)(srow + 4 * lane) = *(const float4*)(src + 4 * lane);
            if (lane < 8)
                *(float4*)(srow + 256 + 4 * lane) =
                    *(const float4*)(src + 256 + 4 * lane);

            // inhibitory tap rows i = d-k (zero-block when out of range)
            const float* K[4];
            #pragma unroll
            for (int k = 0; k < 4; ++k) {
                const int i = d - k;
                K[k] = ws + (((unsigned)i < 94u) ? (OFF_KI + i * KI_LD) : OFF_Z);
            }
            {
                float w0 = srow[bix + 0], w1 = srow[bix + 1], w2 = srow[bix + 2],
                      w3 = srow[bix + 3], w4 = srow[bix + 4];
                #pragma unroll
                for (int g = 0; g < 31; ++g) {
                    #pragma unroll
                    for (int k = 0; k < 4; ++k) {
                        const float k0 = K[k][3 * g + 0];
                        const float k1 = K[k][3 * g + 1];
                        const float k2 = K[k][3 * g + 2];
                        acc[k * 3 + 0] += k0 * w0 + k1 * w1 + k2 * w2;
                        acc[k * 3 + 1] += k0 * w1 + k1 * w2 + k2 * w3;
                        acc[k * 3 + 2] += k0 * w2 + k1 * w3 + k2 * w4;
                    }
                    w0 = w3; w1 = w4;
                    w2 = srow[bix + 3 * g + 5];
                    w3 = srow[bix + 3 * g + 6];
                    w4 = srow[bix + 3 * g + 7];
                }
                #pragma unroll
                for (int k = 0; k < 4; ++k) {
                    const float k93 = K[k][93];
                    acc[k * 3 + 0] += k93 * w0;
                    acc[k * 3 + 1] += k93 * w1;
                    acc[k * 3 + 2] += k93 * w2;
                }
            }

            // excitatory: same staged row; e = d-28-k; skip if none valid
            if (d >= 28 && d <= 68) {
                const float* E[4];
                #pragma unroll
                for (int k = 0; k < 4; ++k) {
                    const int e = d - 28 - k;
                    E[k] = ws + (((unsigned)e < 38u) ? (OFF_KE + e * KE_LD) : OFF_Z);
                }
                float v0 = srow[bix + 28], v1 = srow[bix + 29], v2 = srow[bix + 30],
                      v3 = srow[bix + 31], v4 = srow[bix + 32];
                #pragma unroll
                for (int g = 0; g < 12; ++g) {
                    #pragma unroll
                    for (int k = 0; k < 4; ++k) {
                        const float k0 = E[k][3 * g + 0];
                        const float k1 = E[k][3 * g + 1];
                        const float k2 = E[k][3 * g + 2];
                        acc[k * 3 + 0] += k0 * v0 + k1 * v1 + k2 * v2;
                        acc[k * 3 + 1] += k0 * v1 + k1 * v2 + k2 * v3;
                        acc[k * 3 + 2] += k0 * v2 + k1 * v3 + k2 * v4;
                    }
                    v0 = v3; v1 = v4;
                    v2 = srow[bix + 28 + 3 * g + 5];
                    v3 = srow[bix + 28 + 3 * g + 6];
                    v4 = srow[bix + 28 + 3 * g + 7];
                }
                #pragma unroll
                for (int k = 0; k < 4; ++k) {
                    const float k36 = E[k][36], k37 = E[k][37];
                    acc[k * 3 + 0] += k36 * v0 + k37 * v1;
                    acc[k * 3 + 1] += k36 * v1 + k37 * v2;
                    acc[k * 3 + 2] += k36 * v2 + k37 * v3;
                }
            }
        }

        #pragma unroll
        for (int k = 0; k < 4; ++k) {
            float* op = out + (size_t)(rowid0 + k) * YD + bix;
            atomicAdd(op + 0, acc[k * 3 + 0]);
            atomicAdd(op + 1, acc[k * 3 + 1]);
            atomicAdd(op + 2, acc[k * 3 + 2]);
        }

    } else {
        // ---------------- afferent (round-8 verbatim) ----------------
        const int wv_id = __builtin_amdgcn_readfirstlane(tid >> 6);
        const int xy    = (bid - NCONV) * 4 + wv_id;
        const int lane  = tid & 63;
        const int sx = rfstart[xy * 2 + 0];
        const int sy = rfstart[xy * 2 + 1];
        const f32x4* W4 = (const f32x4*)affw + (size_t)xy * 144;
        const f32x4* M4 = (const f32x4*)affm;

        f32x4 wv[7], mv[7], iv[7];

        // phase 1: issue ALL 21 loads via volatile asm (stay in flight together)
        #pragma unroll
        for (int it = 0; it < 7; ++it) {
            const int g0 = lane + (it << 6);
            const int g  = (g0 < 432) ? g0 : 0;      // clamp tail (in-bounds)
            const int c  = (g >= 288) ? 2 : ((g >= 144) ? 1 : 0);
            const int r  = g - c * 144;
            const f32x4* wp = W4 + (size_t)c * 5308416 + r;   // 36864*144
            asm volatile("global_load_dwordx4 %0, %1, off"
                         : "=v"(wv[it]) : "v"(wp));
            const int u  = (r * 2731) >> 14;         // r/6
            const int v  = (r - u * 6) << 2;
            const float* ip = input + c * (IMG * IMG) + (sx + u) * IMG + (sy + v);
            asm volatile("global_load_dwordx4 %0, %1, off"
                         : "=v"(iv[it]) : "v"(ip));
            const f32x4* mp = M4 + r;
            asm volatile("global_load_dwordx4 %0, %1, off"
                         : "=v"(mv[it]) : "v"(mp));
        }
        asm volatile("s_waitcnt vmcnt(0)" ::: "memory");
        __builtin_amdgcn_sched_barrier(0);

        // phase 2: consume
        float acc = 0.f;
        #pragma unroll
        for (int it = 0; it < 7; ++it) {
            const int g0 = lane + (it << 6);
            const float z = (g0 < 432) ? 1.f : 0.f;  // kill clamped tail
            acc += iv[it].x * (z * mv[it].x) * wv[it].x;
            acc += iv[it].y * (z * mv[it].y) * wv[it].y;
            acc += iv[it].z * (z * mv[it].z) * wv[it].z;
            acc += iv[it].w * (z * mv[it].w) * wv[it].w;
        }
        #pragma unroll
        for (int off = 32; off > 0; off >>= 1) acc += __shfl_xor(acc, off);
        if (lane < 3) atomicAdd(out + (size_t)lane * (XD * YD) + xy, acc);
    }
}

extern "C" void kernel_launch(void* const* d_in, const int* in_sizes, int n_in,
                              void* d_out, int out_size, void* d_ws, size_t ws_size,
                              hipStream_t stream)
{
    const float* input   = (const float*)d_in[0];
    const float* affw    = (const float*)d_in[1];
    const float* exw     = (const float*)d_in[2];
    const float* inw     = (const float*)d_in[3];
    const float* affm    = (const float*)d_in[4];
    const float* exm     = (const float*)d_in[5];
    const float* inm     = (const float*)d_in[6];
    const float* oldact  = (const float*)d_in[7];
    const int*   rfstart = (const int*)d_in[8];
    float* out = (float*)d_out;
    float* ws  = (float*)d_ws;

    hipLaunchKernelGGL(k_prep, dim3(1122), dim3(256), 0, stream,
                       exw, exm, inw, inm, oldact, ws, out);

    hipLaunchKernelGGL(k_fused, dim3(NCONV + NAFF), dim3(256), 0, stream,
                       input, affw, affm, rfstart, ws, out);
}

// Round 12
// 359.353 us; speedup vs baseline: 1.8169x; 1.8169x over previous
//
#include <hip/hip_runtime.h>

#define XD 192
#define YD 192
#define CCH 3
#define IMG 224

// ---- ws layout (float offsets) ----
// padrow[t] = old[c][r][t-47] for t in [47, 239), zero elsewhere; t in [0,288)
#define PADW 288
#define OFF_PAD 0
#define N_PAD (CCH*XD*PADW)             // 165888
#define OFF_KI (OFF_PAD + N_PAD)
#define KI_LD 96                        // 94 taps + 2 zero pad
#define N_KI (94*KI_LD)
#define OFF_KE (OFF_KI + N_KI)
#define KE_LD 40                        // 38 taps + 2 zero pad
#define N_KE (38*KE_LD)
#define OFF_Z (OFF_KE + N_KE)           // 96 zeros (taps for out-of-range rows)
#define N_Z 96

#define N_OUT (CCH*XD*YD)               // 110592

// conv: 288 pair-groups (2 output rows each) * 8 r-phases = 2304 waves = 576 blocks
#define QS 8
#define NCONV 576
#define NAFF 9216                       // 36864 pixels / 4 waves per block

typedef __attribute__((ext_vector_type(4))) float f32x4;

// Prep: zero output, build shifted-pad activation rows, masked gamma-prescaled
// lateral kernels, and the zero-tap block in ws.
__global__ __launch_bounds__(256) void k_prep(
    const float* __restrict__ exw, const float* __restrict__ exm,
    const float* __restrict__ inw, const float* __restrict__ inm,
    const float* __restrict__ oldact, float* __restrict__ ws,
    float* __restrict__ out)
{
    const int TOT = N_OUT + N_PAD + N_KI + N_KE + N_Z;
    for (int idx = blockIdx.x * 256 + threadIdx.x; idx < TOT; idx += gridDim.x * 256) {
        if (idx < N_OUT) {
            out[idx] = 0.f;
        } else if (idx < N_OUT + N_PAD) {
            const int k = idx - N_OUT;
            const int t = k % PADW;
            const int rem = k / PADW;            // c*XD + r
            float v = 0.f;
            if (t >= 47 && t < 47 + YD)
                v = oldact[rem * YD + (t - 47)];
            ws[OFF_PAD + k] = v;
        } else if (idx < N_OUT + N_PAD + N_KI) {
            const int k = idx - N_OUT - N_PAD;
            const int i = k / KI_LD, j = k % KI_LD;
            ws[OFF_KI + k] = (j < 94) ? (-0.9f * inw[i * 94 + j] * inm[i * 94 + j]) : 0.f;
        } else if (idx < N_OUT + N_PAD + N_KI + N_KE) {
            const int k = idx - N_OUT - N_PAD - N_KI;
            const int i = k / KE_LD, j = k % KE_LD;
            ws[OFF_KE + k] = (j < 38) ? (0.9f * exw[i * 38 + j] * exm[i * 38 + j]) : 0.f;
        } else {
            ws[OFF_Z + (idx - N_OUT - N_PAD - N_KI - N_KE)] = 0.f;
        }
    }
}

// Fused kernel:
//  blocks [0, NCONV): lateral conv. One wave owns TWO consecutive output rows
//    (x0, x0+1), 3 cols per lane. Each staged activation row (wave-private LDS
//    slice, no barriers) feeds both rows via two NAMED tap pointers -> 18 FMA
//    per 3-float LDS refill, half the staging of round 8. All state in named
//    scalars (no arrays -> no scratch; round-11 lesson).
//  blocks [NCONV, ...): afferent, round-8 verbatim (asm 21-load batch).
__global__ __launch_bounds__(256, 3) void k_fused(
    const float* __restrict__ input, const float* __restrict__ affw,
    const float* __restrict__ affm, const int* __restrict__ rfstart,
    const float* __restrict__ ws, float* __restrict__ out)
{
    __shared__ float s_row[4][PADW];    // 4.6 KB; per-wave private slices

    const int bid = blockIdx.x;
    const int tid = threadIdx.x;

    if (bid < NCONV) {
        // ---------------- lateral conv ----------------
        const int w    = tid >> 6;
        const int lane = tid & 63;
        const int rgq  = bid * 4 + w;       // 0..2303
        const int q    = rgq & (QS - 1);    // r-phase 0..7
        const int pg   = rgq >> 3;          // pair-group 0..287
        const int rowid0 = pg * 2;          // = c*192 + x0 (never straddles c)
        const int c    = rowid0 / XD;
        const int x0   = rowid0 - c * XD;

        float* srow = &s_row[w][0];
        const float* padc = ws + OFF_PAD + (size_t)(c * XD) * PADW;
        const int bix = 3 * lane;

        float acc0 = 0.f, acc1 = 0.f, acc2 = 0.f;   // row x0
        float acc3 = 0.f, acc4 = 0.f, acc5 = 0.f;   // row x0+1

        for (int r = x0 - 47 + q; r <= x0 + 47; r += QS) {
            if ((unsigned)r >= (unsigned)XD) continue;   // wave-uniform
            const int d = r - x0 + 47;                   // 0..94

            // ---- stage padrow r into this wave's LDS slice (coalesced) ----
            const float* src = padc + r * PADW;
            *(float4*)(srow + 4 * lane) = *(const float4*)(src + 4 * lane);
            if (lane < 8)
                *(float4*)(srow + 256 + 4 * lane) =
                    *(const float4*)(src + 256 + 4 * lane);

            // ---- inhibitory: taps i0=d (row x0), i1=d-1 (row x0+1) ----
            const float* ki0 = ws + (((unsigned)d       < 94u) ? (OFF_KI + d * KI_LD)       : OFF_Z);
            const float* ki1 = ws + (((unsigned)(d - 1) < 94u) ? (OFF_KI + (d - 1) * KI_LD) : OFF_Z);
            {
                float a0 = srow[bix + 0], a1 = srow[bix + 1], a2 = srow[bix + 2],
                      a3 = srow[bix + 3], a4 = srow[bix + 4];
                #pragma unroll
                for (int g = 0; g < 31; ++g) {
                    const float p0 = ki0[3 * g + 0];
                    const float p1 = ki0[3 * g + 1];
                    const float p2 = ki0[3 * g + 2];
                    acc0 += p0 * a0 + p1 * a1 + p2 * a2;
                    acc1 += p0 * a1 + p1 * a2 + p2 * a3;
                    acc2 += p0 * a2 + p1 * a3 + p2 * a4;
                    const float s0 = ki1[3 * g + 0];
                    const float s1 = ki1[3 * g + 1];
                    const float s2 = ki1[3 * g + 2];
                    acc3 += s0 * a0 + s1 * a1 + s2 * a2;
                    acc4 += s0 * a1 + s1 * a2 + s2 * a3;
                    acc5 += s0 * a2 + s1 * a3 + s2 * a4;
                    a0 = a3; a1 = a4;
                    a2 = srow[bix + 3 * g + 5];
                    a3 = srow[bix + 3 * g + 6];
                    a4 = srow[bix + 3 * g + 7];
                }
                const float p93 = ki0[93];
                acc0 += p93 * a0; acc1 += p93 * a1; acc2 += p93 * a2;
                const float s93 = ki1[93];
                acc3 += s93 * a0; acc4 += s93 * a1; acc5 += s93 * a2;
            }

            // ---- excitatory: taps e0=d-28 (row x0), e1=d-29 (row x0+1) ----
            if (d >= 27 && d <= 66) {
                const float* ke0 = ws + (((unsigned)(d - 28) < 38u) ? (OFF_KE + (d - 28) * KE_LD) : OFF_Z);
                const float* ke1 = ws + (((unsigned)(d - 29) < 38u) ? (OFF_KE + (d - 29) * KE_LD) : OFF_Z);
                float b0 = srow[bix + 28], b1 = srow[bix + 29], b2 = srow[bix + 30],
                      b3 = srow[bix + 31], b4 = srow[bix + 32];
                #pragma unroll
                for (int g = 0; g < 12; ++g) {
                    const float p0 = ke0[3 * g + 0];
                    const float p1 = ke0[3 * g + 1];
                    const float p2 = ke0[3 * g + 2];
                    acc0 += p0 * b0 + p1 * b1 + p2 * b2;
                    acc1 += p0 * b1 + p1 * b2 + p2 * b3;
                    acc2 += p0 * b2 + p1 * b3 + p2 * b4;
                    const float s0 = ke1[3 * g + 0];
                    const float s1 = ke1[3 * g + 1];
                    const float s2 = ke1[3 * g + 2];
                    acc3 += s0 * b0 + s1 * b1 + s2 * b2;
                    acc4 += s0 * b1 + s1 * b2 + s2 * b3;
                    acc5 += s0 * b2 + s1 * b3 + s2 * b4;
                    b0 = b3; b1 = b4;
                    b2 = srow[bix + 28 + 3 * g + 5];
                    b3 = srow[bix + 28 + 3 * g + 6];
                    b4 = srow[bix + 28 + 3 * g + 7];
                }
                const float p36 = ke0[36], p37 = ke0[37];
                acc0 += p36 * b0 + p37 * b1;
                acc1 += p36 * b1 + p37 * b2;
                acc2 += p36 * b2 + p37 * b3;
                const float s36 = ke1[36], s37 = ke1[37];
                acc3 += s36 * b0 + s37 * b1;
                acc4 += s36 * b1 + s37 * b2;
                acc5 += s36 * b2 + s37 * b3;
            }
        }

        float* op0 = out + (size_t)rowid0 * YD + bix;
        atomicAdd(op0 + 0, acc0);
        atomicAdd(op0 + 1, acc1);
        atomicAdd(op0 + 2, acc2);
        float* op1 = op0 + YD;
        atomicAdd(op1 + 0, acc3);
        atomicAdd(op1 + 1, acc4);
        atomicAdd(op1 + 2, acc5);

    } else {
        // ---------------- afferent (round-8 verbatim) ----------------
        const int wv_id = __builtin_amdgcn_readfirstlane(tid >> 6);
        const int xy    = (bid - NCONV) * 4 + wv_id;
        const int lane  = tid & 63;
        const int sx = rfstart[xy * 2 + 0];
        const int sy = rfstart[xy * 2 + 1];
        const f32x4* W4 = (const f32x4*)affw + (size_t)xy * 144;
        const f32x4* M4 = (const f32x4*)affm;

        f32x4 wv[7], mv[7], iv[7];

        // phase 1: issue ALL 21 loads via volatile asm (stay in flight together)
        #pragma unroll
        for (int it = 0; it < 7; ++it) {
            const int g0 = lane + (it << 6);
            const int g  = (g0 < 432) ? g0 : 0;      // clamp tail (in-bounds)
            const int c  = (g >= 288) ? 2 : ((g >= 144) ? 1 : 0);
            const int r  = g - c * 144;
            const f32x4* wp = W4 + (size_t)c * 5308416 + r;   // 36864*144
            asm volatile("global_load_dwordx4 %0, %1, off"
                         : "=v"(wv[it]) : "v"(wp));
            const int u  = (r * 2731) >> 14;         // r/6
            const int v  = (r - u * 6) << 2;
            const float* ip = input + c * (IMG * IMG) + (sx + u) * IMG + (sy + v);
            asm volatile("global_load_dwordx4 %0, %1, off"
                         : "=v"(iv[it]) : "v"(ip));
            const f32x4* mp = M4 + r;
            asm volatile("global_load_dwordx4 %0, %1, off"
                         : "=v"(mv[it]) : "v"(mp));
        }
        asm volatile("s_waitcnt vmcnt(0)" ::: "memory");
        __builtin_amdgcn_sched_barrier(0);

        // phase 2: consume
        float acc = 0.f;
        #pragma unroll
        for (int it = 0; it < 7; ++it) {
            const int g0 = lane + (it << 6);
            const float z = (g0 < 432) ? 1.f : 0.f;  // kill clamped tail
            acc += iv[it].x * (z * mv[it].x) * wv[it].x;
            acc += iv[it].y * (z * mv[it].y) * wv[it].y;
            acc += iv[it].z * (z * mv[it].z) * wv[it].z;
            acc += iv[it].w * (z * mv[it].w) * wv[it].w;
        }
        #pragma unroll
        for (int off = 32; off > 0; off >>= 1) acc += __shfl_xor(acc, off);
        if (lane < 3) atomicAdd(out + (size_t)lane * (XD * YD) + xy, acc);
    }
}

extern "C" void kernel_launch(void* const* d_in, const int* in_sizes, int n_in,
                              void* d_out, int out_size, void* d_ws, size_t ws_size,
                              hipStream_t stream)
{
    const float* input   = (const float*)d_in[0];
    const float* affw    = (const float*)d_in[1];
    const float* exw     = (const float*)d_in[2];
    const float* inw     = (const float*)d_in[3];
    const float* affm    = (const float*)d_in[4];
    const float* exm     = (const float*)d_in[5];
    const float* inm     = (const float*)d_in[6];
    const float* oldact  = (const float*)d_in[7];
    const int*   rfstart = (const int*)d_in[8];
    float* out = (float*)d_out;
    float* ws  = (float*)d_ws;

    hipLaunchKernelGGL(k_prep, dim3(1122), dim3(256), 0, stream,
                       exw, exm, inw, inm, oldact, ws, out);

    hipLaunchKernelGGL(k_fused, dim3(NCONV + NAFF), dim3(256), 0, stream,
                       input, affw, affm, rfstart, ws, out);
}

// Round 13
// 117.304 us; speedup vs baseline: 5.5659x; 3.0634x over previous
//
#include <hip/hip_runtime.h>

#define XD 192
#define YD 192
#define CCH 3
#define IMG 224

// ---- ws layout (float offsets) ----
// padrow[t] = old[c][r][t-47] for t in [47, 239), zero elsewhere; t in [0,288)
#define PADW 288
#define OFF_PAD 0
#define N_PAD (CCH*XD*PADW)             // 165888
#define OFF_KI (OFF_PAD + N_PAD)
#define KI_LD 96                        // 94 taps + 2 zero pad
#define N_KI (94*KI_LD)
#define OFF_KE (OFF_KI + N_KI)
#define KE_LD 40                        // 38 taps + 2 zero pad
#define N_KE (38*KE_LD)

#define N_OUT (CCH*XD*YD)               // 110592

#define QS 4
#define NCONV 576                       // 144 row-groups (4 rows) * 4 phases
#define NAFF 9216                       // 36864 pixels / 4 waves per block
#define NTOT (NCONV + NAFF)             // 9792 = 576 * 17

typedef __attribute__((ext_vector_type(4))) float f32x4;

// Prep: zero output, build shifted-pad activation rows and masked,
// gamma-prescaled lateral kernels in ws.
__global__ __launch_bounds__(256) void k_prep(
    const float* __restrict__ exw, const float* __restrict__ exm,
    const float* __restrict__ inw, const float* __restrict__ inm,
    const float* __restrict__ oldact, float* __restrict__ ws,
    float* __restrict__ out)
{
    const int TOT = N_OUT + N_PAD + N_KI + N_KE;
    for (int idx = blockIdx.x * 256 + threadIdx.x; idx < TOT; idx += gridDim.x * 256) {
        if (idx < N_OUT) {
            out[idx] = 0.f;
        } else if (idx < N_OUT + N_PAD) {
            const int k = idx - N_OUT;
            const int t = k % PADW;
            const int rem = k / PADW;            // c*XD + r
            float v = 0.f;
            if (t >= 47 && t < 47 + YD)
                v = oldact[rem * YD + (t - 47)];
            ws[OFF_PAD + k] = v;
        } else if (idx < N_OUT + N_PAD + N_KI) {
            const int k = idx - N_OUT - N_PAD;
            const int i = k / KI_LD, j = k % KI_LD;
            ws[OFF_KI + k] = (j < 94) ? (-0.9f * inw[i * 94 + j] * inm[i * 94 + j]) : 0.f;
        } else {
            const int k = idx - N_OUT - N_PAD - N_KI;
            const int i = k / KE_LD, j = k % KE_LD;
            ws[OFF_KE + k] = (j < 38) ? (0.9f * exw[i * 38 + j] * exm[i * 38 + j]) : 0.f;
        }
    }
}

// Fused kernel, round-8 bodies, with conv/afferent blocks INTERLEAVED
// (bid % 17 == 0 -> conv; 9792/17 = 576 exactly) so every CU holds a mix
// of VALU-bound conv waves and memory-bound afferent waves for the whole
// kernel duration (phase overlap instead of phase concatenation).
__global__ __launch_bounds__(256, 3) void k_fused(
    const float* __restrict__ input, const float* __restrict__ affw,
    const float* __restrict__ affm, const int* __restrict__ rfstart,
    const float* __restrict__ ws, float* __restrict__ out)
{
    __shared__ float s_row[4][PADW];    // 4.6 KB; per-wave private slices

    const int bid = blockIdx.x;
    const int tid = threadIdx.x;
    const int cix = bid / 17;           // conv id if bid%17==0

    if (bid % 17 == 0) {
        // ---------------- lateral conv (round-8 verbatim body) ----------------
        const int grp  = cix >> 2;          // 0..143
        const int q    = cix & 3;           // phase
        const int w    = tid >> 6;          // wave 0..3
        const int lane = tid & 63;
        const int rowid = grp * 4 + w;      // 0..575 = c*192 + x
        const int c = rowid / XD;
        const int x = rowid - c * XD;

        float* srow = &s_row[w][0];
        const float* padc = ws + OFF_PAD + (size_t)(c * XD) * PADW;
        const int bix = 3 * lane;

        float acc0 = 0.f, acc1 = 0.f, acc2 = 0.f;

        for (int i = q; i < 94; i += QS) {
            const int r = x + i - 47;                 // wave-uniform
            if ((unsigned)r >= (unsigned)XD) continue;

            // stage padrow r into this wave's LDS slice (coalesced)
            const float* src = padc + r * PADW;
            *(float4*)(srow + 4 * lane) = *(const float4*)(src + 4 * lane);
            if (lane < 8)
                *(float4*)(srow + 256 + 4 * lane) =
                    *(const float4*)(src + 256 + 4 * lane);

            // inhibitory row i: 94 taps (weights pre-scaled by -0.9)
            {
                const float* ki = ws + OFF_KI + i * KI_LD;
                float a0 = srow[bix + 0], a1 = srow[bix + 1], a2 = srow[bix + 2];
                float a3 = srow[bix + 3], a4 = srow[bix + 4];
                #pragma unroll
                for (int g = 0; g < 31; ++g) {
                    const float k0 = ki[3 * g + 0];
                    const float k1 = ki[3 * g + 1];
                    const float k2 = ki[3 * g + 2];
                    acc0 += k0 * a0 + k1 * a1 + k2 * a2;
                    acc1 += k0 * a1 + k1 * a2 + k2 * a3;
                    acc2 += k0 * a2 + k1 * a3 + k2 * a4;
                    a0 = a3; a1 = a4;
                    a2 = srow[bix + 3 * g + 5];
                    a3 = srow[bix + 3 * g + 6];
                    a4 = srow[bix + 3 * g + 7];
                }
                const float k93 = ki[93];
                acc0 += k93 * a0; acc1 += k93 * a1; acc2 += k93 * a2;
            }

            // excitatory: same staged row, i_exc = i - 28
            if ((unsigned)(i - 28) < 38u) {
                const float* ke = ws + OFF_KE + (i - 28) * KE_LD;
                float b0 = srow[bix + 28], b1 = srow[bix + 29], b2 = srow[bix + 30];
                float b3 = srow[bix + 31], b4 = srow[bix + 32];
                #pragma unroll
                for (int g = 0; g < 12; ++g) {
                    const float k0 = ke[3 * g + 0];
                    const float k1 = ke[3 * g + 1];
                    const float k2 = ke[3 * g + 2];
                    acc0 += k0 * b0 + k1 * b1 + k2 * b2;
                    acc1 += k0 * b1 + k1 * b2 + k2 * b3;
                    acc2 += k0 * b2 + k1 * b3 + k2 * b4;
                    b0 = b3; b1 = b4;
                    b2 = srow[bix + 28 + 3 * g + 5];
                    b3 = srow[bix + 28 + 3 * g + 6];
                    b4 = srow[bix + 28 + 3 * g + 7];
                }
                const float k36 = ke[36], k37 = ke[37];
                acc0 += k36 * b0 + k37 * b1;
                acc1 += k36 * b1 + k37 * b2;
                acc2 += k36 * b2 + k37 * b3;
            }
        }

        float* op = out + ((size_t)c * XD + x) * YD + 3 * lane;
        atomicAdd(op + 0, acc0);
        atomicAdd(op + 1, acc1);
        atomicAdd(op + 2, acc2);

    } else {
        // ---------------- afferent (round-8 verbatim body) ----------------
        const int abid  = bid - cix - 1;    // 0..9215
        const int wv_id = __builtin_amdgcn_readfirstlane(tid >> 6);
        const int xy    = abid * 4 + wv_id;
        const int lane  = tid & 63;
        const int sx = rfstart[xy * 2 + 0];
        const int sy = rfstart[xy * 2 + 1];
        const f32x4* W4 = (const f32x4*)affw + (size_t)xy * 144;
        const f32x4* M4 = (const f32x4*)affm;

        f32x4 wv[7], mv[7], iv[7];

        // phase 1: issue ALL 21 loads via volatile asm (stay in flight together)
        #pragma unroll
        for (int it = 0; it < 7; ++it) {
            const int g0 = lane + (it << 6);
            const int g  = (g0 < 432) ? g0 : 0;      // clamp tail (in-bounds)
            const int c  = (g >= 288) ? 2 : ((g >= 144) ? 1 : 0);
            const int r  = g - c * 144;
            const f32x4* wp = W4 + (size_t)c * 5308416 + r;   // 36864*144
            asm volatile("global_load_dwordx4 %0, %1, off"
                         : "=v"(wv[it]) : "v"(wp));
            const int u  = (r * 2731) >> 14;         // r/6
            const int v  = (r - u * 6) << 2;
            const float* ip = input + c * (IMG * IMG) + (sx + u) * IMG + (sy + v);
            asm volatile("global_load_dwordx4 %0, %1, off"
                         : "=v"(iv[it]) : "v"(ip));
            const f32x4* mp = M4 + r;
            asm volatile("global_load_dwordx4 %0, %1, off"
                         : "=v"(mv[it]) : "v"(mp));
        }
        asm volatile("s_waitcnt vmcnt(0)" ::: "memory");
        __builtin_amdgcn_sched_barrier(0);

        // phase 2: consume
        float acc = 0.f;
        #pragma unroll
        for (int it = 0; it < 7; ++it) {
            const int g0 = lane + (it << 6);
            const float z = (g0 < 432) ? 1.f : 0.f;  // kill clamped tail
            acc += iv[it].x * (z * mv[it].x) * wv[it].x;
            acc += iv[it].y * (z * mv[it].y) * wv[it].y;
            acc += iv[it].z * (z * mv[it].z) * wv[it].z;
            acc += iv[it].w * (z * mv[it].w) * wv[it].w;
        }
        #pragma unroll
        for (int off = 32; off > 0; off >>= 1) acc += __shfl_xor(acc, off);
        if (lane < 3) atomicAdd(out + (size_t)lane * (XD * YD) + xy, acc);
    }
}

extern "C" void kernel_launch(void* const* d_in, const int* in_sizes, int n_in,
                              void* d_out, int out_size, void* d_ws, size_t ws_size,
                              hipStream_t stream)
{
    const float* input   = (const float*)d_in[0];
    const float* affw    = (const float*)d_in[1];
    const float* exw     = (const float*)d_in[2];
    const float* inw     = (const float*)d_in[3];
    const float* affm    = (const float*)d_in[4];
    const float* exm     = (const float*)d_in[5];
    const float* inm     = (const float*)d_in[6];
    const float* oldact  = (const float*)d_in[7];
    const int*   rfstart = (const int*)d_in[8];
    float* out = (float*)d_out;
    float* ws  = (float*)d_ws;

    hipLaunchKernelGGL(k_prep, dim3(1122), dim3(256), 0, stream,
                       exw, exm, inw, inm, oldact, ws, out);

    hipLaunchKernelGGL(k_fused, dim3(NTOT), dim3(256), 0, stream,
                       input, affw, affm, rfstart, ws, out);
}

// Round 14
// 83.051 us; speedup vs baseline: 7.8615x; 1.4124x over previous
//
#include <hip/hip_runtime.h>

#define XD 192
#define YD 192
#define CCH 3
#define IMG 224

// ---- ws layout (float offsets) ----
// padrow[t] = old[c][r][t-47] for t in [47, 239), zero elsewhere; t in [0,288)
#define PADW 288
#define OFF_PAD 0
#define N_PAD (CCH*XD*PADW)             // 165888
#define OFF_KI (OFF_PAD + N_PAD)
#define KI_LD 96                        // 94 taps + 2 zero pad
#define N_KI (94*KI_LD)
#define OFF_KE (OFF_KI + N_KI)
#define KE_LD 40                        // 38 taps + 2 zero pad
#define N_KE (38*KE_LD)

#define N_OUT (CCH*XD*YD)               // 110592

#define QS 4
#define NCONV 576                       // 144 row-groups (4 rows) * 4 phases
#define NAFF 9216                       // 36864 pixels / 4 waves per block

typedef __attribute__((ext_vector_type(4))) float f32x4;

// Prep: zero output, build shifted-pad activation rows and masked,
// gamma-prescaled lateral kernels in ws.
__global__ __launch_bounds__(256) void k_prep(
    const float* __restrict__ exw, const float* __restrict__ exm,
    const float* __restrict__ inw, const float* __restrict__ inm,
    const float* __restrict__ oldact, float* __restrict__ ws,
    float* __restrict__ out)
{
    const int TOT = N_OUT + N_PAD + N_KI + N_KE;
    for (int idx = blockIdx.x * 256 + threadIdx.x; idx < TOT; idx += gridDim.x * 256) {
        if (idx < N_OUT) {
            out[idx] = 0.f;
        } else if (idx < N_OUT + N_PAD) {
            const int k = idx - N_OUT;
            const int t = k % PADW;
            const int rem = k / PADW;            // c*XD + r
            float v = 0.f;
            if (t >= 47 && t < 47 + YD)
                v = oldact[rem * YD + (t - 47)];
            ws[OFF_PAD + k] = v;
        } else if (idx < N_OUT + N_PAD + N_KI) {
            const int k = idx - N_OUT - N_PAD;
            const int i = k / KI_LD, j = k % KI_LD;
            ws[OFF_KI + k] = (j < 94) ? (-0.9f * inw[i * 94 + j] * inm[i * 94 + j]) : 0.f;
        } else {
            const int k = idx - N_OUT - N_PAD - N_KI;
            const int i = k / KE_LD, j = k % KE_LD;
            ws[OFF_KE + k] = (j < 38) ? (0.9f * exw[i * 38 + j] * exm[i * 38 + j]) : 0.f;
        }
    }
}

// Fused kernel (round-8 structure: conv blocks first, then afferent):
//  blocks [0, NCONV): lateral conv, wave-private LDS row + register sliding
//    window, no barriers (round-8 verbatim).
//  blocks [NCONV, ...): afferent, asm-batched weight+input loads (14 TA
//    instrs); MASKS staged once per wave into LDS and read via ds_read
//    (removes 7 TA instrs / wave from the hot loop -> TA-lookup relief).
__global__ __launch_bounds__(256, 3) void k_fused(
    const float* __restrict__ input, const float* __restrict__ affw,
    const float* __restrict__ affm, const int* __restrict__ rfstart,
    const float* __restrict__ ws, float* __restrict__ out)
{
    __shared__ float smem[4][576];      // conv: row slice [0,288); aff: masks [0,576)

    const int bid = blockIdx.x;
    const int tid = threadIdx.x;

    if (bid < NCONV) {
        // ---------------- lateral conv (round-8 verbatim body) ----------------
        const int grp  = bid >> 2;          // 0..143
        const int q    = bid & 3;           // phase
        const int w    = tid >> 6;          // wave 0..3
        const int lane = tid & 63;
        const int rowid = grp * 4 + w;      // 0..575 = c*192 + x
        const int c = rowid / XD;
        const int x = rowid - c * XD;

        float* srow = &smem[w][0];
        const float* padc = ws + OFF_PAD + (size_t)(c * XD) * PADW;
        const int bix = 3 * lane;

        float acc0 = 0.f, acc1 = 0.f, acc2 = 0.f;

        for (int i = q; i < 94; i += QS) {
            const int r = x + i - 47;                 // wave-uniform
            if ((unsigned)r >= (unsigned)XD) continue;

            // stage padrow r into this wave's LDS slice (coalesced)
            const float* src = padc + r * PADW;
            *(float4*)(srow + 4 * lane) = *(const float4*)(src + 4 * lane);
            if (lane < 8)
                *(float4*)(srow + 256 + 4 * lane) =
                    *(const float4*)(src + 256 + 4 * lane);

            // inhibitory row i: 94 taps (weights pre-scaled by -0.9)
            {
                const float* ki = ws + OFF_KI + i * KI_LD;
                float a0 = srow[bix + 0], a1 = srow[bix + 1], a2 = srow[bix + 2];
                float a3 = srow[bix + 3], a4 = srow[bix + 4];
                #pragma unroll
                for (int g = 0; g < 31; ++g) {
                    const float k0 = ki[3 * g + 0];
                    const float k1 = ki[3 * g + 1];
                    const float k2 = ki[3 * g + 2];
                    acc0 += k0 * a0 + k1 * a1 + k2 * a2;
                    acc1 += k0 * a1 + k1 * a2 + k2 * a3;
                    acc2 += k0 * a2 + k1 * a3 + k2 * a4;
                    a0 = a3; a1 = a4;
                    a2 = srow[bix + 3 * g + 5];
                    a3 = srow[bix + 3 * g + 6];
                    a4 = srow[bix + 3 * g + 7];
                }
                const float k93 = ki[93];
                acc0 += k93 * a0; acc1 += k93 * a1; acc2 += k93 * a2;
            }

            // excitatory: same staged row, i_exc = i - 28
            if ((unsigned)(i - 28) < 38u) {
                const float* ke = ws + OFF_KE + (i - 28) * KE_LD;
                float b0 = srow[bix + 28], b1 = srow[bix + 29], b2 = srow[bix + 30];
                float b3 = srow[bix + 31], b4 = srow[bix + 32];
                #pragma unroll
                for (int g = 0; g < 12; ++g) {
                    const float k0 = ke[3 * g + 0];
                    const float k1 = ke[3 * g + 1];
                    const float k2 = ke[3 * g + 2];
                    acc0 += k0 * b0 + k1 * b1 + k2 * b2;
                    acc1 += k0 * b1 + k1 * b2 + k2 * b3;
                    acc2 += k0 * b2 + k1 * b3 + k2 * b4;
                    b0 = b3; b1 = b4;
                    b2 = srow[bix + 28 + 3 * g + 5];
                    b3 = srow[bix + 28 + 3 * g + 6];
                    b4 = srow[bix + 28 + 3 * g + 7];
                }
                const float k36 = ke[36], k37 = ke[37];
                acc0 += k36 * b0 + k37 * b1;
                acc1 += k36 * b1 + k37 * b2;
                acc2 += k36 * b2 + k37 * b3;
            }
        }

        float* op = out + ((size_t)c * XD + x) * YD + 3 * lane;
        atomicAdd(op + 0, acc0);
        atomicAdd(op + 1, acc1);
        atomicAdd(op + 2, acc2);

    } else {
        // ---------------- afferent ----------------
        const int w     = tid >> 6;
        const int wv_id = __builtin_amdgcn_readfirstlane(w);
        const int xy    = (bid - NCONV) * 4 + wv_id;
        const int lane  = tid & 63;
        const int sx = rfstart[xy * 2 + 0];
        const int sy = rfstart[xy * 2 + 1];
        const f32x4* W4 = (const f32x4*)affw + (size_t)xy * 144;
        const f32x4* M4 = (const f32x4*)affm;

        // one-time: stage all 144 mask f32x4 into this wave's LDS slice
        float* smz = &smem[w][0];
        *(f32x4*)(smz + 4 * lane)         = M4[lane];
        *(f32x4*)(smz + 4 * (lane + 64))  = M4[lane + 64];
        if (lane < 16)
            *(f32x4*)(smz + 4 * (lane + 128)) = M4[lane + 128];

        f32x4 wv[7], iv[7];

        // phase 1: issue weight+input loads via volatile asm (14 in flight)
        #pragma unroll
        for (int it = 0; it < 7; ++it) {
            const int g0 = lane + (it << 6);
            const int g  = (g0 < 432) ? g0 : 0;      // clamp tail (in-bounds)
            const int c  = (g >= 288) ? 2 : ((g >= 144) ? 1 : 0);
            const int r  = g - c * 144;
            const f32x4* wp = W4 + (size_t)c * 5308416 + r;   // 36864*144
            asm volatile("global_load_dwordx4 %0, %1, off"
                         : "=v"(wv[it]) : "v"(wp));
            const int u  = (r * 2731) >> 14;         // r/6
            const int v  = (r - u * 6) << 2;
            const float* ip = input + c * (IMG * IMG) + (sx + u) * IMG + (sy + v);
            asm volatile("global_load_dwordx4 %0, %1, off"
                         : "=v"(iv[it]) : "v"(ip));
        }
        asm volatile("s_waitcnt vmcnt(0)" ::: "memory");
        __builtin_amdgcn_sched_barrier(0);

        // phase 2: consume; masks come from LDS (no TA)
        float acc = 0.f;
        #pragma unroll
        for (int it = 0; it < 7; ++it) {
            const int g0 = lane + (it << 6);
            const int g  = (g0 < 432) ? g0 : 0;
            const int c  = (g >= 288) ? 2 : ((g >= 144) ? 1 : 0);
            const int r  = g - c * 144;
            const f32x4 m4 = *(const f32x4*)(smz + 4 * r);   // ds_read_b128
            const float z = (g0 < 432) ? 1.f : 0.f;          // kill clamped tail
            acc += iv[it].x * (z * m4.x) * wv[it].x;
            acc += iv[it].y * (z * m4.y) * wv[it].y;
            acc += iv[it].z * (z * m4.z) * wv[it].z;
            acc += iv[it].w * (z * m4.w) * wv[it].w;
        }
        #pragma unroll
        for (int off = 32; off > 0; off >>= 1) acc += __shfl_xor(acc, off);
        if (lane < 3) atomicAdd(out + (size_t)lane * (XD * YD) + xy, acc);
    }
}

extern "C" void kernel_launch(void* const* d_in, const int* in_sizes, int n_in,
                              void* d_out, int out_size, void* d_ws, size_t ws_size,
                              hipStream_t stream)
{
    const float* input   = (const float*)d_in[0];
    const float* affw    = (const float*)d_in[1];
    const float* exw     = (const float*)d_in[2];
    const float* inw     = (const float*)d_in[3];
    const float* affm    = (const float*)d_in[4];
    const float* exm     = (const float*)d_in[5];
    const float* inm     = (const float*)d_in[6];
    const float* oldact  = (const float*)d_in[7];
    const int*   rfstart = (const int*)d_in[8];
    float* out = (float*)d_out;
    float* ws  = (float*)d_ws;

    hipLaunchKernelGGL(k_prep, dim3(1122), dim3(256), 0, stream,
                       exw, exm, inw, inm, oldact, ws, out);

    hipLaunchKernelGGL(k_fused, dim3(NCONV + NAFF), dim3(256), 0, stream,
                       input, affw, affm, rfstart, ws, out);
}